// Round 1
// baseline (2574.045 us; speedup 1.0000x reference)
//
#include <hip/hip_runtime.h>
#include <stdint.h>
#include <stddef.h>

#define NNODES 100000
#define NEDGES 3200000
#define INFEAT 512
#define HID 256
#define SMP 32768
#define BNEPS 1e-5f
#define NLEV 17

// associative_scan level sizes/offsets for n=100000 (floor halving)
__device__ __constant__ int kLvlN[NLEV] = {100000,50000,25000,12500,6250,3125,1562,781,390,195,97,48,24,12,6,3,1};
__device__ __constant__ int kLvlO[NLEV] = {0,100000,150000,175000,187500,193750,196875,198437,199218,199608,199803,199900,199948,199972,199984,199990,199993};

__device__ __forceinline__ uint32_t rotl32(uint32_t x, int d) { return (x << d) | (x >> (32 - d)); }

// Threefry-2x32, 20 rounds, JAX key-injection schedule
__device__ __forceinline__ void threefry2x32(uint32_t k0, uint32_t k1, uint32_t& x0, uint32_t& x1) {
  const uint32_t ks0 = k0, ks1 = k1, ks2 = k0 ^ k1 ^ 0x1BD11BDAu;
  x0 += ks0; x1 += ks1;
#define TFR(r) { x0 += x1; x1 = rotl32(x1, r); x1 ^= x0; }
  TFR(13) TFR(15) TFR(26) TFR(6)
  x0 += ks1; x1 += ks2 + 1u;
  TFR(17) TFR(29) TFR(16) TFR(24)
  x0 += ks2; x1 += ks0 + 2u;
  TFR(13) TFR(15) TFR(26) TFR(6)
  x0 += ks0; x1 += ks1 + 3u;
  TFR(17) TFR(29) TFR(16) TFR(24)
  x0 += ks1; x1 += ks2 + 4u;
  TFR(13) TFR(15) TFR(26) TFR(6)
  x0 += ks2; x1 += ks0 + 5u;
#undef TFR
}

__global__ __launch_bounds__(256) void k_deg(const int* __restrict__ erow, int* __restrict__ deg) {
  int i = blockIdx.x * 256 + threadIdx.x;
  if (i < NEDGES) atomicAdd(&deg[erow[i]], 1);
}

__global__ __launch_bounds__(256) void k_prob(const int* __restrict__ deg, float* __restrict__ p) {
  int i = blockIdx.x * 256 + threadIdx.x;
  if (i < NNODES) p[i] = (float)deg[i] / 3200000.0f;  // deg.sum() is exactly 3.2e6 in f32
}

// Bit-exact replica of lax.associative_scan(add) tree used by XLA cumsum on CPU/GPU.
// e: concatenated down-sweep levels (level 0 = p, prefilled). s: scan levels (level 0 = result).
__global__ __launch_bounds__(1024) void k_cumsum(float* __restrict__ e, float* __restrict__ s) {
  // down-sweep: e_{l}[k] = e_{l-1}[2k] + e_{l-1}[2k+1]
  for (int l = 1; l < NLEV; ++l) {
    const float* src = e + kLvlO[l - 1];
    float* dst = e + kLvlO[l];
    const int n = kLvlN[l];
    for (int k = threadIdx.x; k < n; k += 1024) dst[k] = src[2 * k] + src[2 * k + 1];
    __syncthreads();
  }
  if (threadIdx.x == 0) s[kLvlO[NLEV - 1]] = e[kLvlO[NLEV - 1]];
  __syncthreads();
  // up-sweep: s_l[2k+1] = s_{l+1}[k]; s_l[2k+2] = s_{l+1}[k] + e_l[2k+2]; s_l[0] = e_l[0]
  for (int l = NLEV - 2; l >= 0; --l) {
    const float* el = e + kLvlO[l];
    const float* sh = s + kLvlO[l + 1];
    float* sl = s + kLvlO[l];
    const int n = kLvlN[l], nh = kLvlN[l + 1];
    for (int k = threadIdx.x; k < nh; k += 1024) {
      float v = sh[k];
      sl[2 * k + 1] = v;
      if (2 * k + 2 < n) sl[2 * k + 2] = v + el[2 * k + 2];
    }
    if (threadIdx.x == 0) sl[0] = el[0];
    __syncthreads();
  }
}

// jax.random.choice(key(42), p) with partitionable threefry (modern JAX default):
// bits[i] = out0 ^ out1 of threefry(key, (0, i)); u = bitcast((bits>>9)|1.0f)-1; r = p_last*(1-u);
// ind = bisect_left(cum, r). Also builds mapping via segment_max semantics.
__global__ __launch_bounds__(256) void k_sample(const float* __restrict__ cum, int* __restrict__ sampled,
                                                int* __restrict__ mapping, float* __restrict__ outSamp) {
  int i = blockIdx.x * 256 + threadIdx.x;
  if (i >= SMP) return;
  uint32_t x0 = 0u, x1 = (uint32_t)i;
  threefry2x32(0u, 42u, x0, x1);
  uint32_t bits = x0 ^ x1;
  float u = __uint_as_float((bits >> 9) | 0x3f800000u) - 1.0f;
  float one_minus = 1.0f - u;
  float r = cum[NNODES - 1] * one_minus;
  int lo = 0, hi = NNODES;
  while (lo < hi) {
    int mid = (lo + hi) >> 1;
    if (cum[mid] < r) lo = mid + 1; else hi = mid;
  }
  if (lo > NNODES - 1) lo = NNODES - 1;
  sampled[i] = lo;
  outSamp[i] = (float)lo;       // harness reads concat output as f32
  atomicMax(&mapping[lo], i);   // mapping pre-set to -1; unsampled stays <0
}

// C[M=32768, N=256] = gather(A)[.,K] @ B[K,256]; 64x64 tile, 4x4/thread, fp32
__global__ __launch_bounds__(256) void k_gemm(const float* __restrict__ Am, const float* __restrict__ Bm,
                                              float* __restrict__ Cm, const int* __restrict__ gather, int K) {
  __shared__ float As[16][68];
  __shared__ float Bs[16][64];
  const int t = threadIdx.x;
  const int tx = t & 15, ty = t >> 4;
  const int row0 = blockIdx.x * 64, col0 = blockIdx.y * 64;
  const int ar = t >> 2, ak = (t & 3) << 2;
  int arow = row0 + ar;
  if (gather) arow = gather[arow];
  const float* aptr = Am + (size_t)arow * K + ak;
  const int kb = t >> 4, cb = (t & 15) << 2;
  const float* bptr = Bm + (size_t)kb * HID + col0 + cb;
  float acc[4][4] = {};
  for (int k0 = 0; k0 < K; k0 += 16) {
    float4 av = *(const float4*)(aptr + k0);
    float4 bv = *(const float4*)(bptr + (size_t)k0 * HID);
    As[ak + 0][ar] = av.x;
    As[ak + 1][ar] = av.y;
    As[ak + 2][ar] = av.z;
    As[ak + 3][ar] = av.w;
    *(float4*)&Bs[kb][cb] = bv;
    __syncthreads();
#pragma unroll
    for (int kk = 0; kk < 16; ++kk) {
      float4 a = *(const float4*)&As[kk][ty << 2];
      float4 b = *(const float4*)&Bs[kk][tx << 2];
      acc[0][0] = fmaf(a.x, b.x, acc[0][0]); acc[0][1] = fmaf(a.x, b.y, acc[0][1]);
      acc[0][2] = fmaf(a.x, b.z, acc[0][2]); acc[0][3] = fmaf(a.x, b.w, acc[0][3]);
      acc[1][0] = fmaf(a.y, b.x, acc[1][0]); acc[1][1] = fmaf(a.y, b.y, acc[1][1]);
      acc[1][2] = fmaf(a.y, b.z, acc[1][2]); acc[1][3] = fmaf(a.y, b.w, acc[1][3]);
      acc[2][0] = fmaf(a.z, b.x, acc[2][0]); acc[2][1] = fmaf(a.z, b.y, acc[2][1]);
      acc[2][2] = fmaf(a.z, b.z, acc[2][2]); acc[2][3] = fmaf(a.z, b.w, acc[2][3]);
      acc[3][0] = fmaf(a.w, b.x, acc[3][0]); acc[3][1] = fmaf(a.w, b.y, acc[3][1]);
      acc[3][2] = fmaf(a.w, b.z, acc[3][2]); acc[3][3] = fmaf(a.w, b.w, acc[3][3]);
    }
    __syncthreads();
  }
#pragma unroll
  for (int i = 0; i < 4; ++i) {
    float4 v = make_float4(acc[i][0], acc[i][1], acc[i][2], acc[i][3]);
    *(float4*)(Cm + (size_t)(row0 + (ty << 2) + i) * HID + col0 + (tx << 2)) = v;
  }
}

// A[c,:] += S[r,:] over all valid edges (one wave per edge iter, float4 lanes)
__global__ __launch_bounds__(256) void k_scatter_feat(const float* __restrict__ S, float* __restrict__ A,
    const int* __restrict__ erow, const int* __restrict__ ecol, const int* __restrict__ mapping) {
  const int wave = threadIdx.x >> 6, lane = threadIdx.x & 63;
  for (int e = blockIdx.x * 4 + wave; e < NEDGES; e += gridDim.x * 4) {
    int r = mapping[erow[e]];
    int c = mapping[ecol[e]];
    if ((r | c) < 0) continue;
    float4 v = *(const float4*)(S + (size_t)r * HID + lane * 4);
    float* dst = A + (size_t)c * HID + lane * 4;
    unsafeAtomicAdd(dst + 0, v.x);
    unsafeAtomicAdd(dst + 1, v.y);
    unsafeAtomicAdd(dst + 2, v.z);
    unsafeAtomicAdd(dst + 3, v.w);
  }
}

__global__ __launch_bounds__(256) void k_bn_stats(const float* __restrict__ A, const float* __restrict__ bias,
                                                  float* __restrict__ sums, float* __restrict__ sumsq) {
  const int c = threadIdx.x;
  const float b = bias[c];
  float s = 0.f, q = 0.f;
  const int r0 = blockIdx.x * (SMP / 256);
  for (int r = r0; r < r0 + (SMP / 256); ++r) {
    float h = A[(size_t)r * HID + c] + b;
    s += h;
    q = fmaf(h, h, q);
  }
  unsafeAtomicAdd(&sums[c], s);
  unsafeAtomicAdd(&sumsq[c], q);
}

__global__ __launch_bounds__(256) void k_bn_final(const float* __restrict__ sums, const float* __restrict__ sumsq,
    const float* __restrict__ gamma, const float* __restrict__ beta,
    float* __restrict__ scale, float* __restrict__ shift) {
  int c = threadIdx.x;
  float mu = sums[c] * (1.0f / SMP);
  float var = fmaxf(sumsq[c] * (1.0f / SMP) - mu * mu, 0.0f);
  float sc = gamma[c] / sqrtf(var + BNEPS);
  scale[c] = sc;
  shift[c] = beta[c] - mu * sc;
}

__global__ __launch_bounds__(256) void k_bn_apply(const float* __restrict__ A, const float* __restrict__ bias,
    const float* __restrict__ scale, const float* __restrict__ shift, float* __restrict__ Hh) {
  const int total = SMP * HID / 4;
  for (int i = blockIdx.x * 256 + threadIdx.x; i < total; i += gridDim.x * 256) {
    int c = (i & (HID / 4 - 1)) * 4;
    float4 v = ((const float4*)A)[i];
    v.x = fmaxf(fmaf(v.x + bias[c + 0], scale[c + 0], shift[c + 0]), 0.f);
    v.y = fmaxf(fmaf(v.y + bias[c + 1], scale[c + 1], shift[c + 1]), 0.f);
    v.z = fmaxf(fmaf(v.z + bias[c + 2], scale[c + 2], shift[c + 2]), 0.f);
    v.w = fmaxf(fmaf(v.w + bias[c + 3], scale[c + 3], shift[c + 3]), 0.f);
    ((float4*)Hh)[i] = v;
  }
}

// s3[i] = dot(H[i,:], W3[:,0]); one wave per row
__global__ __launch_bounds__(256) void k_gemv3(const float* __restrict__ Hh, const float* __restrict__ W3,
                                               float* __restrict__ s3) {
  const int wave = threadIdx.x >> 6, lane = threadIdx.x & 63;
  const int row = blockIdx.x * 4 + wave;
  float4 h = *(const float4*)(Hh + (size_t)row * HID + lane * 4);
  float4 w = *(const float4*)(W3 + lane * 4);
  float d = h.x * w.x + h.y * w.y + h.z * w.z + h.w * w.w;
#pragma unroll
  for (int o = 32; o > 0; o >>= 1) d += __shfl_down(d, o);
  if (lane == 0) s3[row] = d;
}

__global__ __launch_bounds__(256) void k_scatter_sc(const float* __restrict__ s3, float* __restrict__ acc3,
    const int* __restrict__ erow, const int* __restrict__ ecol, const int* __restrict__ mapping) {
  const int stride = gridDim.x * 256;
  for (int e = blockIdx.x * 256 + threadIdx.x; e < NEDGES; e += stride) {
    int r = mapping[erow[e]];
    int c = mapping[ecol[e]];
    if ((r | c) < 0) continue;
    unsafeAtomicAdd(&acc3[c], s3[r]);
  }
}

__global__ __launch_bounds__(256) void k_out(const float* __restrict__ acc3, const float* __restrict__ b3,
                                             float* __restrict__ out) {
  int i = blockIdx.x * 256 + threadIdx.x;
  if (i < SMP) out[i] = acc3[i] + b3[0];
}

extern "C" void kernel_launch(void* const* d_in, const int* in_sizes, int n_in,
                              void* d_out, int out_size, void* d_ws, size_t ws_size,
                              hipStream_t stream) {
  (void)in_sizes; (void)n_in; (void)out_size; (void)ws_size;
  const float* x   = (const float*)d_in[0];
  const int*  eidx = (const int*)d_in[1];
  const float* W1  = (const float*)d_in[2];
  const float* b1  = (const float*)d_in[3];
  const float* W2  = (const float*)d_in[4];
  const float* b2  = (const float*)d_in[5];
  const float* W3  = (const float*)d_in[6];
  const float* b3  = (const float*)d_in[7];
  const float* g1  = (const float*)d_in[8];
  const float* be1 = (const float*)d_in[9];
  const float* g2  = (const float*)d_in[10];
  const float* be2 = (const float*)d_in[11];
  const int* erow = eidx;
  const int* ecol = eidx + NEDGES;

  float* out = (float*)d_out;        // [32768] conv3 output
  float* outSamp = out + SMP;        // [32768] sampled indices as f32

  size_t off = 0;
  auto take = [&](size_t bytes) -> char* {
    char* p = (char*)d_ws + off;
    off += (bytes + 255) & ~(size_t)255;
    return p;
  };
  float* S       = (float*)take((size_t)SMP * HID * 4);  // support / s3
  float* A       = (float*)take((size_t)SMP * HID * 4);  // scatter accumulator
  float* H       = (float*)take((size_t)SMP * HID * 4);  // post-BN activations
  float* E       = (float*)take(199994 * 4);             // cumsum down-sweep levels (L0 = p)
  float* CS      = (float*)take(199994 * 4);             // cumsum up-sweep levels (L0 = result)
  int*   deg     = (int*)take(NNODES * 4);
  int*   mapping = (int*)take(NNODES * 4);
  int*   sampled = (int*)take(SMP * 4);
  float* acc3    = (float*)take(SMP * 4);
  float* sums    = (float*)take(HID * 4 * 2);
  float* sumsq   = sums + HID;
  float* scale   = (float*)take(HID * 4);
  float* shift   = (float*)take(HID * 4);
  // total ws need ~= 102 MB

  hipMemsetAsync(deg, 0, NNODES * 4, stream);
  hipMemsetAsync(mapping, 0xFF, NNODES * 4, stream);  // -1 everywhere

  k_deg<<<(NEDGES + 255) / 256, 256, 0, stream>>>(erow, deg);
  k_prob<<<(NNODES + 255) / 256, 256, 0, stream>>>(deg, E);
  k_cumsum<<<1, 1024, 0, stream>>>(E, CS);
  k_sample<<<SMP / 256, 256, 0, stream>>>(CS, sampled, mapping, outSamp);

  // layer 1: conv(x@W1) -> BN -> relu
  k_gemm<<<dim3(SMP / 64, HID / 64), 256, 0, stream>>>(x, W1, S, sampled, INFEAT);
  hipMemsetAsync(A, 0, (size_t)SMP * HID * 4, stream);
  k_scatter_feat<<<8192, 256, 0, stream>>>(S, A, erow, ecol, mapping);
  hipMemsetAsync(sums, 0, HID * 4 * 2, stream);
  k_bn_stats<<<256, 256, 0, stream>>>(A, b1, sums, sumsq);
  k_bn_final<<<1, HID, 0, stream>>>(sums, sumsq, g1, be1, scale, shift);
  k_bn_apply<<<2048, 256, 0, stream>>>(A, b1, scale, shift, H);

  // layer 2
  k_gemm<<<dim3(SMP / 64, HID / 64), 256, 0, stream>>>(H, W2, S, nullptr, HID);
  hipMemsetAsync(A, 0, (size_t)SMP * HID * 4, stream);
  k_scatter_feat<<<8192, 256, 0, stream>>>(S, A, erow, ecol, mapping);
  hipMemsetAsync(sums, 0, HID * 4 * 2, stream);
  k_bn_stats<<<256, 256, 0, stream>>>(A, b2, sums, sumsq);
  k_bn_final<<<1, HID, 0, stream>>>(sums, sumsq, g2, be2, scale, shift);
  k_bn_apply<<<2048, 256, 0, stream>>>(A, b2, scale, shift, H);

  // layer 3: gemv + scalar scatter + bias
  k_gemv3<<<SMP / 4, 256, 0, stream>>>(H, W3, S);  // S reused as s3
  hipMemsetAsync(acc3, 0, SMP * 4, stream);
  k_scatter_sc<<<2048, 256, 0, stream>>>(S, acc3, erow, ecol, mapping);
  k_out<<<SMP / 256, 256, 0, stream>>>(acc3, b3, out);
}

// Round 2
// 911.653 us; speedup vs baseline: 2.8235x; 2.8235x over previous
//
#include <hip/hip_runtime.h>
#include <stdint.h>
#include <stddef.h>

#define NNODES 100000
#define NEDGES 3200000
#define INFEAT 512
#define HID 256
#define SMP 32768
#define BNEPS 1e-5f
#define NLEV 17

// associative_scan level sizes/offsets for n=100000 (floor halving)
__device__ __constant__ int kLvlN[NLEV] = {100000,50000,25000,12500,6250,3125,1562,781,390,195,97,48,24,12,6,3,1};
__device__ __constant__ int kLvlO[NLEV] = {0,100000,150000,175000,187500,193750,196875,198437,199218,199608,199803,199900,199948,199972,199984,199990,199993};

__device__ __forceinline__ uint32_t rotl32(uint32_t x, int d) { return (x << d) | (x >> (32 - d)); }

// Threefry-2x32, 20 rounds, JAX key-injection schedule — bit-exact, DO NOT TOUCH (verified R1)
__device__ __forceinline__ void threefry2x32(uint32_t k0, uint32_t k1, uint32_t& x0, uint32_t& x1) {
  const uint32_t ks0 = k0, ks1 = k1, ks2 = k0 ^ k1 ^ 0x1BD11BDAu;
  x0 += ks0; x1 += ks1;
#define TFR(r) { x0 += x1; x1 = rotl32(x1, r); x1 ^= x0; }
  TFR(13) TFR(15) TFR(26) TFR(6)
  x0 += ks1; x1 += ks2 + 1u;
  TFR(17) TFR(29) TFR(16) TFR(24)
  x0 += ks2; x1 += ks0 + 2u;
  TFR(13) TFR(15) TFR(26) TFR(6)
  x0 += ks0; x1 += ks1 + 3u;
  TFR(17) TFR(29) TFR(16) TFR(24)
  x0 += ks1; x1 += ks2 + 4u;
  TFR(13) TFR(15) TFR(26) TFR(6)
  x0 += ks2; x1 += ks0 + 5u;
#undef TFR
}

__global__ __launch_bounds__(256) void k_deg(const int* __restrict__ erow, int* __restrict__ deg) {
  int i = blockIdx.x * 256 + threadIdx.x;
  if (i < NEDGES) atomicAdd(&deg[erow[i]], 1);
}

__global__ __launch_bounds__(256) void k_prob(const int* __restrict__ deg, float* __restrict__ p) {
  int i = blockIdx.x * 256 + threadIdx.x;
  if (i < NNODES) p[i] = (float)deg[i] / 3200000.0f;  // deg.sum() is exactly 3.2e6 in f32
}

// Bit-exact replica of lax.associative_scan(add) tree used by XLA cumsum — verified R1
__global__ __launch_bounds__(1024) void k_cumsum(float* __restrict__ e, float* __restrict__ s) {
  for (int l = 1; l < NLEV; ++l) {
    const float* src = e + kLvlO[l - 1];
    float* dst = e + kLvlO[l];
    const int n = kLvlN[l];
    for (int k = threadIdx.x; k < n; k += 1024) dst[k] = src[2 * k] + src[2 * k + 1];
    __syncthreads();
  }
  if (threadIdx.x == 0) s[kLvlO[NLEV - 1]] = e[kLvlO[NLEV - 1]];
  __syncthreads();
  for (int l = NLEV - 2; l >= 0; --l) {
    const float* el = e + kLvlO[l];
    const float* sh = s + kLvlO[l + 1];
    float* sl = s + kLvlO[l];
    const int n = kLvlN[l], nh = kLvlN[l + 1];
    for (int k = threadIdx.x; k < nh; k += 1024) {
      float v = sh[k];
      sl[2 * k + 1] = v;
      if (2 * k + 2 < n) sl[2 * k + 2] = v + el[2 * k + 2];
    }
    if (threadIdx.x == 0) sl[0] = el[0];
    __syncthreads();
  }
}

// partitionable-threefry choice + searchsorted left — bit-exact, verified R1
__global__ __launch_bounds__(256) void k_sample(const float* __restrict__ cum, int* __restrict__ sampled,
                                                int* __restrict__ mapping, float* __restrict__ outSamp) {
  int i = blockIdx.x * 256 + threadIdx.x;
  if (i >= SMP) return;
  uint32_t x0 = 0u, x1 = (uint32_t)i;
  threefry2x32(0u, 42u, x0, x1);
  uint32_t bits = x0 ^ x1;
  float u = __uint_as_float((bits >> 9) | 0x3f800000u) - 1.0f;
  float r = cum[NNODES - 1] * (1.0f - u);
  int lo = 0, hi = NNODES;
  while (lo < hi) {
    int mid = (lo + hi) >> 1;
    if (cum[mid] < r) lo = mid + 1; else hi = mid;
  }
  if (lo > NNODES - 1) lo = NNODES - 1;
  sampled[i] = lo;
  outSamp[i] = (float)lo;
  atomicMax(&mapping[lo], i);
}

// ---- CSR build over valid edges keyed by destination position ----
__global__ __launch_bounds__(256) void k_edge_count(const int* __restrict__ erow, const int* __restrict__ ecol,
                                                    const int* __restrict__ mapping, int* __restrict__ cnt) {
  int i = blockIdx.x * 256 + threadIdx.x;
  if (i >= NEDGES) return;
  int r = mapping[erow[i]];
  int c = mapping[ecol[i]];
  if ((r | c) >= 0) atomicAdd(&cnt[c], 1);
}

__global__ __launch_bounds__(1024) void k_scan(const int* __restrict__ cnt, int* __restrict__ rowptr,
                                               int* __restrict__ cursor) {
  __shared__ int tot[1024];
  const int t = threadIdx.x;
  const int base = t * 32;
  int local[32];
  int s = 0;
#pragma unroll
  for (int i = 0; i < 32; ++i) { local[i] = s; s += cnt[base + i]; }
  tot[t] = s;
  __syncthreads();
  for (int o = 1; o < 1024; o <<= 1) {
    int v = (t >= o) ? tot[t - o] : 0;
    __syncthreads();
    tot[t] += v;
    __syncthreads();
  }
  int excl = (t == 0) ? 0 : tot[t - 1];
#pragma unroll
  for (int i = 0; i < 32; ++i) {
    int v = excl + local[i];
    rowptr[base + i] = v;
    cursor[base + i] = v;
  }
  if (t == 1023) rowptr[SMP] = tot[1023];
}

__global__ __launch_bounds__(256) void k_edge_fill(const int* __restrict__ erow, const int* __restrict__ ecol,
                                                   const int* __restrict__ mapping, int* __restrict__ cursor,
                                                   int* __restrict__ srcidx) {
  int i = blockIdx.x * 256 + threadIdx.x;
  if (i >= NEDGES) return;
  int r = mapping[erow[i]];
  int c = mapping[ecol[i]];
  if ((r | c) < 0) return;
  int pos = atomicAdd(&cursor[c], 1);
  srcidx[pos] = r;
}

// A[c,:] = sum over CSR bucket of S[r,:] — one wave per destination, no atomics
__global__ __launch_bounds__(256) void k_segsum(const float* __restrict__ S, const int* __restrict__ rowptr,
                                                const int* __restrict__ srcidx, float* __restrict__ A) {
  const int wave = threadIdx.x >> 6, lane = threadIdx.x & 63;
  const int c = blockIdx.x * 4 + wave;
  const int b = rowptr[c], e = rowptr[c + 1];
  float4 acc = make_float4(0.f, 0.f, 0.f, 0.f);
  for (int i = b; i < e; ++i) {
    int r = srcidx[i];
    float4 v = *(const float4*)(S + (size_t)r * HID + lane * 4);
    acc.x += v.x; acc.y += v.y; acc.z += v.z; acc.w += v.w;
  }
  *(float4*)(A + (size_t)c * HID + lane * 4) = acc;
}

// out[c] = sum s3[r] + b3 — one thread per destination
__global__ __launch_bounds__(256) void k_segsum_sc(const float* __restrict__ s3, const int* __restrict__ rowptr,
                                                   const int* __restrict__ srcidx, const float* __restrict__ b3,
                                                   float* __restrict__ out) {
  int c = blockIdx.x * 256 + threadIdx.x;
  if (c >= SMP) return;
  float acc = 0.f;
  const int e = rowptr[c + 1];
  for (int i = rowptr[c]; i < e; ++i) acc += s3[srcidx[i]];
  out[c] = acc + b3[0];
}

// C[M=32768, N=256] = gather(A)[.,K] @ B[K,256]; 64x64 tile, 4x4/thread, fp32
__global__ __launch_bounds__(256) void k_gemm(const float* __restrict__ Am, const float* __restrict__ Bm,
                                              float* __restrict__ Cm, const int* __restrict__ gather, int K) {
  __shared__ float As[16][68];
  __shared__ float Bs[16][64];
  const int t = threadIdx.x;
  const int tx = t & 15, ty = t >> 4;
  const int row0 = blockIdx.x * 64, col0 = blockIdx.y * 64;
  const int ar = t >> 2, ak = (t & 3) << 2;
  int arow = row0 + ar;
  if (gather) arow = gather[arow];
  const float* aptr = Am + (size_t)arow * K + ak;
  const int kb = t >> 4, cb = (t & 15) << 2;
  const float* bptr = Bm + (size_t)kb * HID + col0 + cb;
  float acc[4][4] = {};
  for (int k0 = 0; k0 < K; k0 += 16) {
    float4 av = *(const float4*)(aptr + k0);
    float4 bv = *(const float4*)(bptr + (size_t)k0 * HID);
    As[ak + 0][ar] = av.x;
    As[ak + 1][ar] = av.y;
    As[ak + 2][ar] = av.z;
    As[ak + 3][ar] = av.w;
    *(float4*)&Bs[kb][cb] = bv;
    __syncthreads();
#pragma unroll
    for (int kk = 0; kk < 16; ++kk) {
      float4 a = *(const float4*)&As[kk][ty << 2];
      float4 b = *(const float4*)&Bs[kk][tx << 2];
      acc[0][0] = fmaf(a.x, b.x, acc[0][0]); acc[0][1] = fmaf(a.x, b.y, acc[0][1]);
      acc[0][2] = fmaf(a.x, b.z, acc[0][2]); acc[0][3] = fmaf(a.x, b.w, acc[0][3]);
      acc[1][0] = fmaf(a.y, b.x, acc[1][0]); acc[1][1] = fmaf(a.y, b.y, acc[1][1]);
      acc[1][2] = fmaf(a.y, b.z, acc[1][2]); acc[1][3] = fmaf(a.y, b.w, acc[1][3]);
      acc[2][0] = fmaf(a.z, b.x, acc[2][0]); acc[2][1] = fmaf(a.z, b.y, acc[2][1]);
      acc[2][2] = fmaf(a.z, b.z, acc[2][2]); acc[2][3] = fmaf(a.z, b.w, acc[2][3]);
      acc[3][0] = fmaf(a.w, b.x, acc[3][0]); acc[3][1] = fmaf(a.w, b.y, acc[3][1]);
      acc[3][2] = fmaf(a.w, b.z, acc[3][2]); acc[3][3] = fmaf(a.w, b.w, acc[3][3]);
    }
    __syncthreads();
  }
#pragma unroll
  for (int i = 0; i < 4; ++i) {
    float4 v = make_float4(acc[i][0], acc[i][1], acc[i][2], acc[i][3]);
    *(float4*)(Cm + (size_t)(row0 + (ty << 2) + i) * HID + col0 + (tx << 2)) = v;
  }
}

__global__ __launch_bounds__(256) void k_bn_stats(const float* __restrict__ A, const float* __restrict__ bias,
                                                  float* __restrict__ sums, float* __restrict__ sumsq) {
  const int c = threadIdx.x;
  const float b = bias[c];
  float s = 0.f, q = 0.f;
  const int r0 = blockIdx.x * (SMP / 256);
  for (int r = r0; r < r0 + (SMP / 256); ++r) {
    float h = A[(size_t)r * HID + c] + b;
    s += h;
    q = fmaf(h, h, q);
  }
  unsafeAtomicAdd(&sums[c], s);
  unsafeAtomicAdd(&sumsq[c], q);
}

__global__ __launch_bounds__(256) void k_bn_final(const float* __restrict__ sums, const float* __restrict__ sumsq,
    const float* __restrict__ gamma, const float* __restrict__ beta,
    float* __restrict__ scale, float* __restrict__ shift) {
  int c = threadIdx.x;
  float mu = sums[c] * (1.0f / SMP);
  float var = fmaxf(sumsq[c] * (1.0f / SMP) - mu * mu, 0.0f);
  float sc = gamma[c] / sqrtf(var + BNEPS);
  scale[c] = sc;
  shift[c] = beta[c] - mu * sc;
}

__global__ __launch_bounds__(256) void k_bn_apply(const float* __restrict__ A, const float* __restrict__ bias,
    const float* __restrict__ scale, const float* __restrict__ shift, float* __restrict__ Hh) {
  const int total = SMP * HID / 4;
  for (int i = blockIdx.x * 256 + threadIdx.x; i < total; i += gridDim.x * 256) {
    int c = (i & (HID / 4 - 1)) * 4;
    float4 v = ((const float4*)A)[i];
    v.x = fmaxf(fmaf(v.x + bias[c + 0], scale[c + 0], shift[c + 0]), 0.f);
    v.y = fmaxf(fmaf(v.y + bias[c + 1], scale[c + 1], shift[c + 1]), 0.f);
    v.z = fmaxf(fmaf(v.z + bias[c + 2], scale[c + 2], shift[c + 2]), 0.f);
    v.w = fmaxf(fmaf(v.w + bias[c + 3], scale[c + 3], shift[c + 3]), 0.f);
    ((float4*)Hh)[i] = v;
  }
}

// s3[i] = dot(H[i,:], W3[:,0]); one wave per row
__global__ __launch_bounds__(256) void k_gemv3(const float* __restrict__ Hh, const float* __restrict__ W3,
                                               float* __restrict__ s3) {
  const int wave = threadIdx.x >> 6, lane = threadIdx.x & 63;
  const int row = blockIdx.x * 4 + wave;
  float4 h = *(const float4*)(Hh + (size_t)row * HID + lane * 4);
  float4 w = *(const float4*)(W3 + lane * 4);
  float d = h.x * w.x + h.y * w.y + h.z * w.z + h.w * w.w;
#pragma unroll
  for (int o = 32; o > 0; o >>= 1) d += __shfl_down(d, o);
  if (lane == 0) s3[row] = d;
}

extern "C" void kernel_launch(void* const* d_in, const int* in_sizes, int n_in,
                              void* d_out, int out_size, void* d_ws, size_t ws_size,
                              hipStream_t stream) {
  (void)in_sizes; (void)n_in; (void)out_size; (void)ws_size;
  const float* x   = (const float*)d_in[0];
  const int*  eidx = (const int*)d_in[1];
  const float* W1  = (const float*)d_in[2];
  const float* b1  = (const float*)d_in[3];
  const float* W2  = (const float*)d_in[4];
  const float* b2  = (const float*)d_in[5];
  const float* W3  = (const float*)d_in[6];
  const float* b3  = (const float*)d_in[7];
  const float* g1  = (const float*)d_in[8];
  const float* be1 = (const float*)d_in[9];
  const float* g2  = (const float*)d_in[10];
  const float* be2 = (const float*)d_in[11];
  const int* erow = eidx;
  const int* ecol = eidx + NEDGES;

  float* out = (float*)d_out;        // [32768] conv3 output
  float* outSamp = out + SMP;        // [32768] sampled indices as f32

  size_t off = 0;
  auto take = [&](size_t bytes) -> char* {
    char* p = (char*)d_ws + off;
    off += (bytes + 255) & ~(size_t)255;
    return p;
  };
  float* S       = (float*)take((size_t)SMP * HID * 4);  // support / s3
  float* A       = (float*)take((size_t)SMP * HID * 4);  // segsum output
  float* H       = (float*)take((size_t)SMP * HID * 4);  // post-BN activations
  float* E       = (float*)take(199994 * 4);             // cumsum down-sweep levels
  float* CS      = (float*)take(199994 * 4);             // cumsum up-sweep levels
  int*   deg     = (int*)take(NNODES * 4);
  int*   mapping = (int*)take(NNODES * 4);
  int*   sampled = (int*)take(SMP * 4);
  float* sums    = (float*)take(HID * 4 * 2);
  float* sumsq   = sums + HID;
  float* scale   = (float*)take(HID * 4);
  float* shift   = (float*)take(HID * 4);
  int*   cnt     = (int*)take(SMP * 4);
  int*   rowptr  = (int*)take((SMP + 1) * 4);
  int*   cursor  = (int*)take(SMP * 4);
  int*   srcidx  = (int*)take((size_t)NEDGES * 4);       // worst-case all edges valid
  // total ws need ~= 115 MB

  hipMemsetAsync(deg, 0, NNODES * 4, stream);
  hipMemsetAsync(mapping, 0xFF, NNODES * 4, stream);  // -1 everywhere
  hipMemsetAsync(cnt, 0, SMP * 4, stream);

  k_deg<<<(NEDGES + 255) / 256, 256, 0, stream>>>(erow, deg);
  k_prob<<<(NNODES + 255) / 256, 256, 0, stream>>>(deg, E);
  k_cumsum<<<1, 1024, 0, stream>>>(E, CS);
  k_sample<<<SMP / 256, 256, 0, stream>>>(CS, sampled, mapping, outSamp);

  // CSR over valid edges, keyed by destination position
  k_edge_count<<<(NEDGES + 255) / 256, 256, 0, stream>>>(erow, ecol, mapping, cnt);
  k_scan<<<1, 1024, 0, stream>>>(cnt, rowptr, cursor);
  k_edge_fill<<<(NEDGES + 255) / 256, 256, 0, stream>>>(erow, ecol, mapping, cursor, srcidx);

  // layer 1: conv(x@W1) -> BN -> relu
  k_gemm<<<dim3(SMP / 64, HID / 64), 256, 0, stream>>>(x, W1, S, sampled, INFEAT);
  k_segsum<<<SMP / 4, 256, 0, stream>>>(S, rowptr, srcidx, A);
  hipMemsetAsync(sums, 0, HID * 4 * 2, stream);
  k_bn_stats<<<256, 256, 0, stream>>>(A, b1, sums, sumsq);
  k_bn_final<<<1, HID, 0, stream>>>(sums, sumsq, g1, be1, scale, shift);
  k_bn_apply<<<2048, 256, 0, stream>>>(A, b1, scale, shift, H);

  // layer 2
  k_gemm<<<dim3(SMP / 64, HID / 64), 256, 0, stream>>>(H, W2, S, nullptr, HID);
  k_segsum<<<SMP / 4, 256, 0, stream>>>(S, rowptr, srcidx, A);
  hipMemsetAsync(sums, 0, HID * 4 * 2, stream);
  k_bn_stats<<<256, 256, 0, stream>>>(A, b2, sums, sumsq);
  k_bn_final<<<1, HID, 0, stream>>>(sums, sumsq, g2, be2, scale, shift);
  k_bn_apply<<<2048, 256, 0, stream>>>(A, b2, scale, shift, H);

  // layer 3: gemv + CSR segsum + bias
  k_gemv3<<<SMP / 4, 256, 0, stream>>>(H, W3, S);  // S reused as s3
  k_segsum_sc<<<SMP / 256, 256, 0, stream>>>(S, rowptr, srcidx, b3, out);
}

// Round 3
// 800.011 us; speedup vs baseline: 3.2175x; 1.1396x over previous
//
#include <hip/hip_runtime.h>
#include <stdint.h>
#include <stddef.h>

#define NNODES 100000
#define NEDGES 3200000
#define INFEAT 512
#define HID 256
#define SMP 32768
#define BNEPS 1e-5f

__device__ __forceinline__ uint32_t rotl32(uint32_t x, int d) { return (x << d) | (x >> (32 - d)); }

// Threefry-2x32, 20 rounds, JAX key-injection schedule — bit-exact, DO NOT TOUCH (verified R1)
__device__ __forceinline__ void threefry2x32(uint32_t k0, uint32_t k1, uint32_t& x0, uint32_t& x1) {
  const uint32_t ks0 = k0, ks1 = k1, ks2 = k0 ^ k1 ^ 0x1BD11BDAu;
  x0 += ks0; x1 += ks1;
#define TFR(r) { x0 += x1; x1 = rotl32(x1, r); x1 ^= x0; }
  TFR(13) TFR(15) TFR(26) TFR(6)
  x0 += ks1; x1 += ks2 + 1u;
  TFR(17) TFR(29) TFR(16) TFR(24)
  x0 += ks2; x1 += ks0 + 2u;
  TFR(13) TFR(15) TFR(26) TFR(6)
  x0 += ks0; x1 += ks1 + 3u;
  TFR(17) TFR(29) TFR(16) TFR(24)
  x0 += ks1; x1 += ks2 + 4u;
  TFR(13) TFR(15) TFR(26) TFR(6)
  x0 += ks2; x1 += ks0 + 5u;
#undef TFR
}

__global__ __launch_bounds__(256) void k_deg(const int* __restrict__ erow, int* __restrict__ deg) {
  int i = blockIdx.x * 256 + threadIdx.x;
  if (i < NEDGES) atomicAdd(&deg[erow[i]], 1);
}

// ---- cumsum = bit-exact replica of XLA associative_scan tree, parallelized ----
// Down-sweep levels 0..4 (p computed from deg inline; levels 1-4 divide evenly).
// Each block: 4096 level-0 elements -> levels 1..4 in LDS ping-pong, written to E.
__global__ __launch_bounds__(256) void k_down(const int* __restrict__ deg, float* __restrict__ E) {
  __shared__ float l0[4096];
  __shared__ float l1[2048];
  const int t = threadIdx.x;
  const int base0 = blockIdx.x * 4096;
  const int n0 = min(4096, NNODES - base0);
  for (int i = t; i < n0; i += 256) {
    float p = (float)deg[base0 + i] / 3200000.0f;  // deg.sum() exactly 3.2e6 in f32
    l0[i] = p;
    E[base0 + i] = p;
  }
  __syncthreads();
  const int b1 = base0 >> 1, n1 = min(2048, 50000 - b1);
  for (int k = t; k < n1; k += 256) { float v = l0[2*k] + l0[2*k+1]; l1[k] = v; E[100000 + b1 + k] = v; }
  __syncthreads();
  const int b2 = base0 >> 2, n2 = min(1024, 25000 - b2);
  for (int k = t; k < n2; k += 256) { float v = l1[2*k] + l1[2*k+1]; l0[k] = v; E[150000 + b2 + k] = v; }
  __syncthreads();
  const int b3 = base0 >> 3, n3 = min(512, 12500 - b3);
  for (int k = t; k < n3; k += 256) { float v = l0[2*k] + l0[2*k+1]; l1[k] = v; E[175000 + b3 + k] = v; }
  __syncthreads();
  const int b4 = base0 >> 4, n4 = min(256, 6250 - b4);
  for (int k = t; k < n4; k += 256) { float v = l1[2*k] + l1[2*k+1]; E[187500 + b4 + k] = v; }
}

// Levels 5..16 down-sweep + 16..5 up-sweep, entirely in LDS (≈49 KB), one block.
__device__ __constant__ int kMidN[12] = {3125,1562,781,390,195,97,48,24,12,6,3,1};
__device__ __constant__ int kMidO[12] = {0,3125,4687,5468,5858,6053,6150,6198,6222,6234,6240,6243};
__global__ __launch_bounds__(1024) void k_mid(const float* __restrict__ E, float* __restrict__ CS) {
  __shared__ float eb[6244];
  __shared__ float sb[6244];
  const int t = threadIdx.x;
  const float* e4 = E + 187500;
  for (int k = t; k < 3125; k += 1024) eb[k] = e4[2*k] + e4[2*k+1];
  __syncthreads();
  for (int li = 1; li < 12; ++li) {
    const float* src = eb + kMidO[li-1];
    float* dst = eb + kMidO[li];
    const int n = kMidN[li];
    for (int k = t; k < n; k += 1024) dst[k] = src[2*k] + src[2*k+1];
    __syncthreads();
  }
  if (t == 0) sb[6243] = eb[6243];  // s16 = e16
  __syncthreads();
  for (int li = 10; li >= 0; --li) {
    const float* el = eb + kMidO[li];
    const float* sh = sb + kMidO[li+1];
    float* sl = sb + kMidO[li];
    const int n = kMidN[li], nh = kMidN[li+1];
    for (int k = t; k < nh; k += 1024) {
      float v = sh[k];
      sl[2*k+1] = v;
      if (2*k+2 < n) sl[2*k+2] = v + el[2*k+2];
    }
    if (t == 0) sl[0] = el[0];
    __syncthreads();
  }
  for (int k = t; k < 3125; k += 1024) CS[193750 + k] = sb[k];  // s5
}

// One up-sweep level: s_l[j] from s_{l+1} and e_l. Same IEEE ops as the serial tree.
__global__ __launch_bounds__(256) void k_up(const float* __restrict__ sh, const float* __restrict__ el,
                                            float* __restrict__ sl, int n) {
  int j = blockIdx.x * 256 + threadIdx.x;
  if (j >= n) return;
  if (j == 0) { sl[0] = el[0]; return; }
  float v = sh[(j - 1) >> 1];
  sl[j] = (j & 1) ? v : v + el[j];
}

// partitionable-threefry choice + searchsorted left — bit-exact, verified R1
__global__ __launch_bounds__(256) void k_sample(const float* __restrict__ cum, int* __restrict__ sampled,
                                                int* __restrict__ mapping, float* __restrict__ outSamp) {
  int i = blockIdx.x * 256 + threadIdx.x;
  if (i >= SMP) return;
  uint32_t x0 = 0u, x1 = (uint32_t)i;
  threefry2x32(0u, 42u, x0, x1);
  uint32_t bits = x0 ^ x1;
  float u = __uint_as_float((bits >> 9) | 0x3f800000u) - 1.0f;
  float r = cum[NNODES - 1] * (1.0f - u);
  int lo = 0, hi = NNODES;
  while (lo < hi) {
    int mid = (lo + hi) >> 1;
    if (cum[mid] < r) lo = mid + 1; else hi = mid;
  }
  if (lo > NNODES - 1) lo = NNODES - 1;
  sampled[i] = lo;
  outSamp[i] = (float)lo;
  atomicMax(&mapping[lo], i);
}

// ---- CSR build over valid edges keyed by destination position ----
__global__ __launch_bounds__(256) void k_edge_count(const int* __restrict__ erow, const int* __restrict__ ecol,
                                                    const int* __restrict__ mapping, int* __restrict__ cnt) {
  int i = blockIdx.x * 256 + threadIdx.x;
  if (i >= NEDGES) return;
  int r = mapping[erow[i]];
  int c = mapping[ecol[i]];
  if ((r | c) >= 0) atomicAdd(&cnt[c], 1);
}

__global__ __launch_bounds__(1024) void k_scan(const int* __restrict__ cnt, int* __restrict__ rowptr,
                                               int* __restrict__ cursor) {
  __shared__ int tot[1024];
  const int t = threadIdx.x;
  const int base = t * 32;
  int local[32];
  int s = 0;
#pragma unroll
  for (int i = 0; i < 32; ++i) { local[i] = s; s += cnt[base + i]; }
  tot[t] = s;
  __syncthreads();
  for (int o = 1; o < 1024; o <<= 1) {
    int v = (t >= o) ? tot[t - o] : 0;
    __syncthreads();
    tot[t] += v;
    __syncthreads();
  }
  int excl = (t == 0) ? 0 : tot[t - 1];
#pragma unroll
  for (int i = 0; i < 32; ++i) {
    int v = excl + local[i];
    rowptr[base + i] = v;
    cursor[base + i] = v;
  }
  if (t == 1023) rowptr[SMP] = tot[1023];
}

__global__ __launch_bounds__(256) void k_edge_fill(const int* __restrict__ erow, const int* __restrict__ ecol,
                                                   const int* __restrict__ mapping, int* __restrict__ cursor,
                                                   int* __restrict__ srcidx) {
  int i = blockIdx.x * 256 + threadIdx.x;
  if (i >= NEDGES) return;
  int r = mapping[erow[i]];
  int c = mapping[ecol[i]];
  if ((r | c) < 0) return;
  int pos = atomicAdd(&cursor[c], 1);
  srcidx[pos] = r;
}

// A[c,:] = sum over CSR bucket of S[r,:] — one wave per destination, no atomics
__global__ __launch_bounds__(256) void k_segsum(const float* __restrict__ S, const int* __restrict__ rowptr,
                                                const int* __restrict__ srcidx, float* __restrict__ A) {
  const int wave = threadIdx.x >> 6, lane = threadIdx.x & 63;
  const int c = blockIdx.x * 4 + wave;
  const int b = rowptr[c], e = rowptr[c + 1];
  float4 acc = make_float4(0.f, 0.f, 0.f, 0.f);
  for (int i = b; i < e; ++i) {
    int r = srcidx[i];
    float4 v = *(const float4*)(S + (size_t)r * HID + lane * 4);
    acc.x += v.x; acc.y += v.y; acc.z += v.z; acc.w += v.w;
  }
  *(float4*)(A + (size_t)c * HID + lane * 4) = acc;
}

// out[c] = sum s3[r] + b3 — one thread per destination
__global__ __launch_bounds__(256) void k_segsum_sc(const float* __restrict__ s3, const int* __restrict__ rowptr,
                                                   const int* __restrict__ srcidx, const float* __restrict__ b3,
                                                   float* __restrict__ out) {
  int c = blockIdx.x * 256 + threadIdx.x;
  if (c >= SMP) return;
  float acc = 0.f;
  const int e = rowptr[c + 1];
  for (int i = rowptr[c]; i < e; ++i) acc += s3[srcidx[i]];
  out[c] = acc + b3[0];
}

// C[M=32768, N=256] = gather(A)[.,K] @ B[K,256]; 64x64 tile, 4x4/thread, fp32
__global__ __launch_bounds__(256) void k_gemm(const float* __restrict__ Am, const float* __restrict__ Bm,
                                              float* __restrict__ Cm, const int* __restrict__ gather, int K) {
  __shared__ float As[16][68];
  __shared__ float Bs[16][64];
  const int t = threadIdx.x;
  const int tx = t & 15, ty = t >> 4;
  const int row0 = blockIdx.x * 64, col0 = blockIdx.y * 64;
  const int ar = t >> 2, ak = (t & 3) << 2;
  int arow = row0 + ar;
  if (gather) arow = gather[arow];
  const float* aptr = Am + (size_t)arow * K + ak;
  const int kb = t >> 4, cb = (t & 15) << 2;
  const float* bptr = Bm + (size_t)kb * HID + col0 + cb;
  float acc[4][4] = {};
  for (int k0 = 0; k0 < K; k0 += 16) {
    float4 av = *(const float4*)(aptr + k0);
    float4 bv = *(const float4*)(bptr + (size_t)k0 * HID);
    As[ak + 0][ar] = av.x;
    As[ak + 1][ar] = av.y;
    As[ak + 2][ar] = av.z;
    As[ak + 3][ar] = av.w;
    *(float4*)&Bs[kb][cb] = bv;
    __syncthreads();
#pragma unroll
    for (int kk = 0; kk < 16; ++kk) {
      float4 a = *(const float4*)&As[kk][ty << 2];
      float4 b = *(const float4*)&Bs[kk][tx << 2];
      acc[0][0] = fmaf(a.x, b.x, acc[0][0]); acc[0][1] = fmaf(a.x, b.y, acc[0][1]);
      acc[0][2] = fmaf(a.x, b.z, acc[0][2]); acc[0][3] = fmaf(a.x, b.w, acc[0][3]);
      acc[1][0] = fmaf(a.y, b.x, acc[1][0]); acc[1][1] = fmaf(a.y, b.y, acc[1][1]);
      acc[1][2] = fmaf(a.y, b.z, acc[1][2]); acc[1][3] = fmaf(a.y, b.w, acc[1][3]);
      acc[2][0] = fmaf(a.z, b.x, acc[2][0]); acc[2][1] = fmaf(a.z, b.y, acc[2][1]);
      acc[2][2] = fmaf(a.z, b.z, acc[2][2]); acc[2][3] = fmaf(a.z, b.w, acc[2][3]);
      acc[3][0] = fmaf(a.w, b.x, acc[3][0]); acc[3][1] = fmaf(a.w, b.y, acc[3][1]);
      acc[3][2] = fmaf(a.w, b.z, acc[3][2]); acc[3][3] = fmaf(a.w, b.w, acc[3][3]);
    }
    __syncthreads();
  }
#pragma unroll
  for (int i = 0; i < 4; ++i) {
    float4 v = make_float4(acc[i][0], acc[i][1], acc[i][2], acc[i][3]);
    *(float4*)(Cm + (size_t)(row0 + (ty << 2) + i) * HID + col0 + (tx << 2)) = v;
  }
}

__global__ __launch_bounds__(256) void k_bn_stats(const float* __restrict__ A, const float* __restrict__ bias,
                                                  float* __restrict__ sums, float* __restrict__ sumsq) {
  const int c = threadIdx.x;
  const float b = bias[c];
  float s = 0.f, q = 0.f;
  const int r0 = blockIdx.x * (SMP / 256);
  for (int r = r0; r < r0 + (SMP / 256); ++r) {
    float h = A[(size_t)r * HID + c] + b;
    s += h;
    q = fmaf(h, h, q);
  }
  unsafeAtomicAdd(&sums[c], s);
  unsafeAtomicAdd(&sumsq[c], q);
}

__global__ __launch_bounds__(256) void k_bn_final(const float* __restrict__ sums, const float* __restrict__ sumsq,
    const float* __restrict__ gamma, const float* __restrict__ beta,
    float* __restrict__ scale, float* __restrict__ shift) {
  int c = threadIdx.x;
  float mu = sums[c] * (1.0f / SMP);
  float var = fmaxf(sumsq[c] * (1.0f / SMP) - mu * mu, 0.0f);
  float sc = gamma[c] / sqrtf(var + BNEPS);
  scale[c] = sc;
  shift[c] = beta[c] - mu * sc;
}

__global__ __launch_bounds__(256) void k_bn_apply(const float* __restrict__ A, const float* __restrict__ bias,
    const float* __restrict__ scale, const float* __restrict__ shift, float* __restrict__ Hh) {
  const int total = SMP * HID / 4;
  for (int i = blockIdx.x * 256 + threadIdx.x; i < total; i += gridDim.x * 256) {
    int c = (i & (HID / 4 - 1)) * 4;
    float4 v = ((const float4*)A)[i];
    v.x = fmaxf(fmaf(v.x + bias[c + 0], scale[c + 0], shift[c + 0]), 0.f);
    v.y = fmaxf(fmaf(v.y + bias[c + 1], scale[c + 1], shift[c + 1]), 0.f);
    v.z = fmaxf(fmaf(v.z + bias[c + 2], scale[c + 2], shift[c + 2]), 0.f);
    v.w = fmaxf(fmaf(v.w + bias[c + 3], scale[c + 3], shift[c + 3]), 0.f);
    ((float4*)Hh)[i] = v;
  }
}

// s3[i] = dot(H[i,:], W3[:,0]); one wave per row
__global__ __launch_bounds__(256) void k_gemv3(const float* __restrict__ Hh, const float* __restrict__ W3,
                                               float* __restrict__ s3) {
  const int wave = threadIdx.x >> 6, lane = threadIdx.x & 63;
  const int row = blockIdx.x * 4 + wave;
  float4 h = *(const float4*)(Hh + (size_t)row * HID + lane * 4);
  float4 w = *(const float4*)(W3 + lane * 4);
  float d = h.x * w.x + h.y * w.y + h.z * w.z + h.w * w.w;
#pragma unroll
  for (int o = 32; o > 0; o >>= 1) d += __shfl_down(d, o);
  if (lane == 0) s3[row] = d;
}

extern "C" void kernel_launch(void* const* d_in, const int* in_sizes, int n_in,
                              void* d_out, int out_size, void* d_ws, size_t ws_size,
                              hipStream_t stream) {
  (void)in_sizes; (void)n_in; (void)out_size; (void)ws_size;
  const float* x   = (const float*)d_in[0];
  const int*  eidx = (const int*)d_in[1];
  const float* W1  = (const float*)d_in[2];
  const float* b1  = (const float*)d_in[3];
  const float* W2  = (const float*)d_in[4];
  const float* b2  = (const float*)d_in[5];
  const float* W3  = (const float*)d_in[6];
  const float* b3  = (const float*)d_in[7];
  const float* g1  = (const float*)d_in[8];
  const float* be1 = (const float*)d_in[9];
  const float* g2  = (const float*)d_in[10];
  const float* be2 = (const float*)d_in[11];
  const int* erow = eidx;
  const int* ecol = eidx + NEDGES;

  float* out = (float*)d_out;        // [32768] conv3 output
  float* outSamp = out + SMP;        // [32768] sampled indices as f32

  size_t off = 0;
  auto take = [&](size_t bytes) -> char* {
    char* p = (char*)d_ws + off;
    off += (bytes + 255) & ~(size_t)255;
    return p;
  };
  float* S       = (float*)take((size_t)SMP * HID * 4);  // support / s3
  float* A       = (float*)take((size_t)SMP * HID * 4);  // segsum output
  float* H       = (float*)take((size_t)SMP * HID * 4);  // post-BN activations
  float* E       = (float*)take(199994 * 4);             // down-sweep levels
  float* CS      = (float*)take(199994 * 4);             // up-sweep levels (CS[0..100000) = result)
  int*   deg     = (int*)take(NNODES * 4);
  int*   mapping = (int*)take(NNODES * 4);
  int*   sampled = (int*)take(SMP * 4);
  float* sums    = (float*)take(HID * 4 * 2);
  float* sumsq   = sums + HID;
  float* scale   = (float*)take(HID * 4);
  float* shift   = (float*)take(HID * 4);
  int*   cnt     = (int*)take(SMP * 4);
  int*   rowptr  = (int*)take((SMP + 1) * 4);
  int*   cursor  = (int*)take(SMP * 4);
  int*   srcidx  = (int*)take((size_t)NEDGES * 4);
  // total ws need ~= 115 MB

  hipMemsetAsync(deg, 0, NNODES * 4, stream);
  hipMemsetAsync(mapping, 0xFF, NNODES * 4, stream);  // -1 everywhere
  hipMemsetAsync(cnt, 0, SMP * 4, stream);

  k_deg<<<(NEDGES + 255) / 256, 256, 0, stream>>>(erow, deg);

  // cumsum: parallel bit-exact tree
  k_down<<<25, 256, 0, stream>>>(deg, E);
  k_mid<<<1, 1024, 0, stream>>>(E, CS);
  k_up<<<(6250 + 255) / 256, 256, 0, stream>>>(CS + 193750, E + 187500, CS + 187500, 6250);
  k_up<<<(12500 + 255) / 256, 256, 0, stream>>>(CS + 187500, E + 175000, CS + 175000, 12500);
  k_up<<<(25000 + 255) / 256, 256, 0, stream>>>(CS + 175000, E + 150000, CS + 150000, 25000);
  k_up<<<(50000 + 255) / 256, 256, 0, stream>>>(CS + 150000, E + 100000, CS + 100000, 50000);
  k_up<<<(100000 + 255) / 256, 256, 0, stream>>>(CS + 100000, E, CS, 100000);

  k_sample<<<SMP / 256, 256, 0, stream>>>(CS, sampled, mapping, outSamp);

  // CSR over valid edges, keyed by destination position
  k_edge_count<<<(NEDGES + 255) / 256, 256, 0, stream>>>(erow, ecol, mapping, cnt);
  k_scan<<<1, 1024, 0, stream>>>(cnt, rowptr, cursor);
  k_edge_fill<<<(NEDGES + 255) / 256, 256, 0, stream>>>(erow, ecol, mapping, cursor, srcidx);

  // layer 1: conv(x@W1) -> BN -> relu
  k_gemm<<<dim3(SMP / 64, HID / 64), 256, 0, stream>>>(x, W1, S, sampled, INFEAT);
  k_segsum<<<SMP / 4, 256, 0, stream>>>(S, rowptr, srcidx, A);
  hipMemsetAsync(sums, 0, HID * 4 * 2, stream);
  k_bn_stats<<<256, 256, 0, stream>>>(A, b1, sums, sumsq);
  k_bn_final<<<1, HID, 0, stream>>>(sums, sumsq, g1, be1, scale, shift);
  k_bn_apply<<<2048, 256, 0, stream>>>(A, b1, scale, shift, H);

  // layer 2
  k_gemm<<<dim3(SMP / 64, HID / 64), 256, 0, stream>>>(H, W2, S, nullptr, HID);
  k_segsum<<<SMP / 4, 256, 0, stream>>>(S, rowptr, srcidx, A);
  hipMemsetAsync(sums, 0, HID * 4 * 2, stream);
  k_bn_stats<<<256, 256, 0, stream>>>(A, b2, sums, sumsq);
  k_bn_final<<<1, HID, 0, stream>>>(sums, sumsq, g2, be2, scale, shift);
  k_bn_apply<<<2048, 256, 0, stream>>>(A, b2, scale, shift, H);

  // layer 3: gemv + CSR segsum + bias
  k_gemv3<<<SMP / 4, 256, 0, stream>>>(H, W3, S);  // S reused as s3
  k_segsum_sc<<<SMP / 256, 256, 0, stream>>>(S, rowptr, srcidx, b3, out);
}